// Round 6
// baseline (1666.131 us; speedup 1.0000x reference)
//
#include <hip/hip_runtime.h>
#include <stdint.h>

#define E_ 8
#define H_ 2048
#define I_ 4096
#define T_ 1024
#define N1_ (2 * I_) /* 8192 */

typedef unsigned short ushort_t;
typedef _Float16 half_t;
typedef __attribute__((ext_vector_type(2))) _Float16 h2;
typedef __attribute__((ext_vector_type(8))) _Float16 f16x8;
typedef __attribute__((ext_vector_type(4))) float f32x4;

// pack two fp32 -> two f16 (RTZ) in one dword: 1 VALU op
__device__ __forceinline__ uint32_t pk2h(float a, float b) {
    auto r = __builtin_amdgcn_cvt_pkrtz(a, b);
    uint32_t u;
    __builtin_memcpy(&u, &r, 4);
    return u;
}

// per-K-step scale: fold gscale*blockscale/64 into a packed f16 pair
__device__ __forceinline__ h2 mk_ss(float sv) {
    half_t h = (half_t)(sv * 0.015625f); // /64: LUT stores value*64
    h2 r; r.x = h; r.y = h;
    return r;
}

// gather byte0 of 4 words -> one dword [b3,b2,b1,b0]
__device__ __forceinline__ unsigned gather4(const int* wtv) {
    unsigned t0 = __builtin_amdgcn_perm((unsigned)wtv[1], (unsigned)wtv[0], 0x0C0C0400u);
    unsigned t1 = __builtin_amdgcn_perm((unsigned)wtv[3], (unsigned)wtv[2], 0x04000C0Cu);
    return t0 | t1;
}

// ---- dequant 4 packed bytes (each = 2 fp4 codes) -> 4 dwords of 2 scaled f16 ----
__device__ __forceinline__ uint4 dq4(unsigned w4, h2 ss) {
    const uint32_t T_LO = 0x56545000u; // codes 0..3 f16-hi of val*64
    const uint32_t T_HI = 0x5E5C5A58u; // codes 4..7
    uint32_t selL = w4 & 0x07070707u;
    uint32_t selH = (w4 >> 4) & 0x07070707u;
    uint32_t hiL = __builtin_amdgcn_perm(T_HI, T_LO, selL) | ((w4 & 0x08080808u) << 4);
    uint32_t hiH = __builtin_amdgcn_perm(T_HI, T_LO, selH) | (w4 & 0x80808080u);
    uint32_t p0 = __builtin_amdgcn_perm(hiH, hiL, 0x040C000Cu);
    uint32_t p1 = __builtin_amdgcn_perm(hiH, hiL, 0x050C010Cu);
    uint32_t p2 = __builtin_amdgcn_perm(hiH, hiL, 0x060C020Cu);
    uint32_t p3 = __builtin_amdgcn_perm(hiH, hiL, 0x070C030Cu);
    uint4 q;
    h2 r0 = *(h2*)&p0 * ss; __builtin_memcpy(&q.x, &r0, 4);
    h2 r1 = *(h2*)&p1 * ss; __builtin_memcpy(&q.y, &r1, 4);
    h2 r2 = *(h2*)&p2 * ss; __builtin_memcpy(&q.z, &r2, 4);
    h2 r3 = *(h2*)&p3 * ss; __builtin_memcpy(&q.w, &r3, 4);
    return q;
}

// ==================== prepass: compact weights int32->byte, 4 k-rows/dword ====================
// dst[e][r4][n] byte j = (byte0 of) src[e][r4*4+j][n]
template<int R4, int NC>
__global__ __launch_bounds__(256) void pack_w_kernel(const int* __restrict__ src,
                                                     unsigned* __restrict__ dst) {
    const size_t total = (size_t)E_ * R4 * NC;
    const size_t stride = (size_t)gridDim.x * 256;
    for (size_t i = (size_t)blockIdx.x * 256 + threadIdx.x; i < total; i += stride) {
        size_t e = i / ((size_t)R4 * NC);
        size_t r4n = i - e * ((size_t)R4 * NC);
        size_t r4 = r4n / NC, n = r4n - r4 * NC;
        const int* s = src + ((e * R4 + r4) * 4) * (size_t)NC + n;
        unsigned w0 = (unsigned)s[0], w1 = (unsigned)s[NC];
        unsigned w2 = (unsigned)s[2 * (size_t)NC], w3 = (unsigned)s[3 * (size_t)NC];
        unsigned t0 = __builtin_amdgcn_perm(w1, w0, 0x0C0C0400u);
        unsigned t1 = __builtin_amdgcn_perm(w3, w2, 0x04000C0Cu);
        dst[i] = t0 | t1;
    }
}

// prepass: x fp32 -> f16 (RTZ, same as gemm1's pk2h path)
__global__ __launch_bounds__(256) void pack_x_kernel(const float* __restrict__ src,
                                                     ushort_t* __restrict__ dst) {
    const size_t total8 = (size_t)E_ * T_ * H_ / 8;
    const size_t stride = (size_t)gridDim.x * 256;
    for (size_t i = (size_t)blockIdx.x * 256 + threadIdx.x; i < total8; i += stride) {
        const float4 a = *(const float4*)(src + i * 8);
        const float4 b = *(const float4*)(src + i * 8 + 4);
        uint4 d;
        d.x = pk2h(a.x, a.y); d.y = pk2h(a.z, a.w);
        d.z = pk2h(b.x, b.y); d.w = pk2h(b.z, b.w);
        *(uint4*)(dst + i * 8) = d;
    }
}

// ==================== GEMM1: x @ dequant(Wgu) + silu, 2-deep prefetch ====================
// MODE 0: raw int32 weights + fp32 x. MODE 1: compact weights. MODE 2: + f16 x.
template<int MODE>
__global__ __launch_bounds__(512, 4) void gemm1_kernel(
    const float* __restrict__ x, const ushort_t* __restrict__ xh,
    const int* __restrict__ gup, const unsigned* __restrict__ gupc,
    const float* __restrict__ gus, const float* __restrict__ gscale_p,
    ushort_t* __restrict__ inter, int e0) {
    __shared__ __align__(16) ushort_t As[2][256 * 40];
    __shared__ __align__(16) ushort_t Bs[2][128 * 40];

    const int tid = threadIdx.x;
    const int lane = tid & 63, wv = tid >> 6;
    const int quad = lane >> 4, c16 = lane & 15;
    const int mw = wv >> 1, nw = wv & 1;
    const int zloc = blockIdx.z, e = e0 + zloc;
    const int mBase = blockIdx.y * 256, nTile = blockIdx.x;
    const float gsc = gscale_p[0];

    const int kq = (tid >> 4) & 3;
    const int bn = (tid & 15) | ((tid >> 6) << 4);
    const int colg = nTile * 64 + (bn & 63) + ((bn >> 6) << 12);
    const int* bptr = gup + (size_t)e * (H_ / 2) * N1_ + (size_t)(kq * 4) * N1_ + colg;
    const unsigned* bptrc = gupc + (size_t)e * (H_ / 8) * N1_ + (size_t)kq * N1_ + colg;
    const float* sptr = gus + (size_t)e * (H_ / 16) * N1_ + (size_t)(kq >> 1) * N1_ + colg;

    const int arow = tid >> 2, seg = tid & 3;
    const float* ap = x + (size_t)(e * T_ + mBase + arow) * H_ + seg * 8;
    const ushort_t* aph = xh + (size_t)(e * T_ + mBase + arow) * H_ + seg * 8;

    f32x4 accg[4][2], accu[4][2];
    const f32x4 z4 = {0.f, 0.f, 0.f, 0.f};
#pragma unroll
    for (int f = 0; f < 4; ++f)
#pragma unroll
        for (int b = 0; b < 2; ++b) { accg[f][b] = z4; accu[f][b] = z4; }

    float4 fa[2][4]; uint4 va[2][2]; int wt[2][4]; unsigned bw[2]; float sv[2];

#define G1_LOAD(b, t) do { \
    if constexpr (MODE == 2) { \
        va[b][0] = *(const uint4*)(aph + (size_t)(t) * 32); \
        va[b][1] = *(const uint4*)(aph + (size_t)128 * H_ + (size_t)(t) * 32); \
    } else { \
        fa[b][0] = *(const float4*)(ap + (size_t)(t) * 32); \
        fa[b][1] = *(const float4*)(ap + (size_t)(t) * 32 + 4); \
        fa[b][2] = *(const float4*)(ap + (size_t)128 * H_ + (size_t)(t) * 32); \
        fa[b][3] = *(const float4*)(ap + (size_t)128 * H_ + (size_t)(t) * 32 + 4); \
    } \
    if constexpr (MODE >= 1) { bw[b] = bptrc[(size_t)(t) * 4 * N1_]; } \
    else { \
        const int* bp_ = bptr + (size_t)(t) * 16 * N1_; \
        wt[b][0] = bp_[0]; wt[b][1] = bp_[(size_t)N1_]; \
        wt[b][2] = bp_[(size_t)2 * N1_]; wt[b][3] = bp_[(size_t)3 * N1_]; \
    } \
    sv[b] = sptr[(size_t)(t) * 2 * N1_] * gsc; \
} while (0)

#define G1_STAGE(b, L) do { \
    if constexpr (MODE == 2) { \
        *(uint4*)(&As[L][arow * 40 + seg * 8]) = va[b][0]; \
        *(uint4*)(&As[L][(arow + 128) * 40 + seg * 8]) = va[b][1]; \
    } else { \
        uint4 d0_, d1_; \
        d0_.x = pk2h(fa[b][0].x, fa[b][0].y); d0_.y = pk2h(fa[b][0].z, fa[b][0].w); \
        d0_.z = pk2h(fa[b][1].x, fa[b][1].y); d0_.w = pk2h(fa[b][1].z, fa[b][1].w); \
        d1_.x = pk2h(fa[b][2].x, fa[b][2].y); d1_.y = pk2h(fa[b][2].z, fa[b][2].w); \
        d1_.z = pk2h(fa[b][3].x, fa[b][3].y); d1_.w = pk2h(fa[b][3].z, fa[b][3].w); \
        *(uint4*)(&As[L][arow * 40 + seg * 8]) = d0_; \
        *(uint4*)(&As[L][(arow + 128) * 40 + seg * 8]) = d1_; \
    } \
    unsigned w4_; \
    if constexpr (MODE >= 1) w4_ = bw[b]; else w4_ = gather4(wt[b]); \
    uint4 q_ = dq4(w4_, mk_ss(sv[b])); \
    *(uint4*)(&Bs[L][bn * 40 + kq * 8]) = q_; \
} while (0)

#define G1_CONSUME(L) do { \
    f16x8 bg0 = *(const f16x8*)(&Bs[L][(nw * 32 + c16) * 40 + quad * 8]); \
    f16x8 bg1 = *(const f16x8*)(&Bs[L][(nw * 32 + 16 + c16) * 40 + quad * 8]); \
    f16x8 bu0 = *(const f16x8*)(&Bs[L][(64 + nw * 32 + c16) * 40 + quad * 8]); \
    f16x8 bu1 = *(const f16x8*)(&Bs[L][(64 + nw * 32 + 16 + c16) * 40 + quad * 8]); \
    _Pragma("unroll") \
    for (int f = 0; f < 4; ++f) { \
        f16x8 af = *(const f16x8*)(&As[L][(mw * 64 + f * 16 + c16) * 40 + quad * 8]); \
        accg[f][0] = __builtin_amdgcn_mfma_f32_16x16x32_f16(af, bg0, accg[f][0], 0, 0, 0); \
        accg[f][1] = __builtin_amdgcn_mfma_f32_16x16x32_f16(af, bg1, accg[f][1], 0, 0, 0); \
        accu[f][0] = __builtin_amdgcn_mfma_f32_16x16x32_f16(af, bu0, accu[f][0], 0, 0, 0); \
        accu[f][1] = __builtin_amdgcn_mfma_f32_16x16x32_f16(af, bu1, accu[f][1], 0, 0, 0); \
    } \
} while (0)

    const int NT = H_ / 32; // 64, even
    G1_LOAD(0, 0);
    G1_LOAD(1, 1);
    G1_STAGE(0, 0);
    __syncthreads();
    for (int kt = 0; kt < NT; kt += 2) {
        // even step: consume lds0 (t=kt); buf1 holds t=kt+1; buf0 free -> load t=kt+2
        if (kt + 2 < NT) G1_LOAD(0, kt + 2);
        G1_CONSUME(0);
        G1_STAGE(1, 1); // t = kt+1 (kt <= NT-2 so always valid)
        __syncthreads();
        // odd step: consume lds1 (t=kt+1); buf0 holds t=kt+2; buf1 free -> load t=kt+3
        if (kt + 3 < NT) G1_LOAD(1, kt + 3);
        G1_CONSUME(1);
        if (kt + 2 < NT) { G1_STAGE(0, 0); __syncthreads(); }
    }
#undef G1_LOAD
#undef G1_STAGE
#undef G1_CONSUME

    // epilogue: inter = up * silu(gate), stored as f16
    ushort_t* ip = inter + (size_t)zloc * T_ * I_;
#pragma unroll
    for (int f = 0; f < 4; ++f)
#pragma unroll
        for (int b = 0; b < 2; ++b)
#pragma unroll
            for (int r = 0; r < 4; ++r) {
                int row = mBase + mw * 64 + f * 16 + quad * 4 + r;
                int col = nTile * 64 + nw * 32 + b * 16 + c16;
                float g = accg[f][b][r];
                float u = accu[f][b][r];
                float v = u * g / (1.f + __expf(-g));
                half_t hv = (half_t)v;
                ushort_t hu;
                __builtin_memcpy(&hu, &hv, 2);
                ip[(size_t)row * I_ + col] = hu;
            }
}

// ==================== GEMM2: inter(f16) @ dequant(Wd) -> fp32, 2-deep prefetch ====================
// MODE 0: raw int32 weights. MODE 1: compact weights.
template<int MODE>
__global__ __launch_bounds__(512, 4) void gemm2_kernel(
    const ushort_t* __restrict__ inter,
    const int* __restrict__ dp, const unsigned* __restrict__ dpc,
    const float* __restrict__ dsc, const float* __restrict__ gscale_p,
    float* __restrict__ out, int e0) {
    __shared__ __align__(16) ushort_t As[2][256 * 40];
    __shared__ __align__(16) ushort_t Bs[2][128 * 40];

    const int tid = threadIdx.x;
    const int lane = tid & 63, wv = tid >> 6;
    const int quad = lane >> 4, c16 = lane & 15;
    const int mw = wv >> 1, nw = wv & 1;
    const int zloc = blockIdx.z, e = e0 + zloc;
    const int mBase = blockIdx.y * 256, nBase = blockIdx.x * 128;
    const float gsc = gscale_p[0];

    const int kq = (tid >> 4) & 3;
    const int bn = (tid & 15) | ((tid >> 6) << 4);
    const int col = nBase + bn;
    const int* bptr = dp + (size_t)e * (I_ / 2) * H_ + (size_t)(kq * 4) * H_ + col;
    const unsigned* bptrc = dpc + (size_t)e * (I_ / 8) * H_ + (size_t)kq * H_ + col;
    const float* sptr = dsc + (size_t)e * (I_ / 16) * H_ + (size_t)(kq >> 1) * H_ + col;

    const int arow = tid >> 2, seg = tid & 3;
    const ushort_t* ap = inter + (size_t)(zloc * T_ + mBase + arow) * I_ + seg * 8;

    f32x4 acc[4][4];
    const f32x4 z4 = {0.f, 0.f, 0.f, 0.f};
#pragma unroll
    for (int f = 0; f < 4; ++f)
#pragma unroll
        for (int b = 0; b < 4; ++b) acc[f][b] = z4;

    uint4 va[2][2]; int wt[2][4]; unsigned bw[2]; float sv[2];

#define G2_LOAD(b, t) do { \
    va[b][0] = *(const uint4*)(ap + (size_t)(t) * 32); \
    va[b][1] = *(const uint4*)(ap + (size_t)128 * I_ + (size_t)(t) * 32); \
    if constexpr (MODE >= 1) { bw[b] = bptrc[(size_t)(t) * 4 * H_]; } \
    else { \
        const int* bp_ = bptr + (size_t)(t) * 16 * H_; \
        wt[b][0] = bp_[0]; wt[b][1] = bp_[(size_t)H_]; \
        wt[b][2] = bp_[(size_t)2 * H_]; wt[b][3] = bp_[(size_t)3 * H_]; \
    } \
    sv[b] = sptr[(size_t)(t) * 2 * H_] * gsc; \
} while (0)

#define G2_STAGE(b, L) do { \
    *(uint4*)(&As[L][arow * 40 + seg * 8]) = va[b][0]; \
    *(uint4*)(&As[L][(arow + 128) * 40 + seg * 8]) = va[b][1]; \
    unsigned w4_; \
    if constexpr (MODE >= 1) w4_ = bw[b]; else w4_ = gather4(wt[b]); \
    uint4 q_ = dq4(w4_, mk_ss(sv[b])); \
    *(uint4*)(&Bs[L][bn * 40 + kq * 8]) = q_; \
} while (0)

#define G2_CONSUME(L) do { \
    f16x8 bfr[4]; \
    _Pragma("unroll") \
    for (int b = 0; b < 4; ++b) \
        bfr[b] = *(const f16x8*)(&Bs[L][(nw * 64 + b * 16 + c16) * 40 + quad * 8]); \
    _Pragma("unroll") \
    for (int f = 0; f < 4; ++f) { \
        f16x8 af = *(const f16x8*)(&As[L][(mw * 64 + f * 16 + c16) * 40 + quad * 8]); \
        _Pragma("unroll") \
        for (int b = 0; b < 4; ++b) \
            acc[f][b] = __builtin_amdgcn_mfma_f32_16x16x32_f16(af, bfr[b], acc[f][b], 0, 0, 0); \
    } \
} while (0)

    const int NT = I_ / 32; // 128, even
    G2_LOAD(0, 0);
    G2_LOAD(1, 1);
    G2_STAGE(0, 0);
    __syncthreads();
    for (int kt = 0; kt < NT; kt += 2) {
        if (kt + 2 < NT) G2_LOAD(0, kt + 2);
        G2_CONSUME(0);
        G2_STAGE(1, 1);
        __syncthreads();
        if (kt + 3 < NT) G2_LOAD(1, kt + 3);
        G2_CONSUME(1);
        if (kt + 2 < NT) { G2_STAGE(0, 0); __syncthreads(); }
    }
#undef G2_LOAD
#undef G2_STAGE
#undef G2_CONSUME

#pragma unroll
    for (int f = 0; f < 4; ++f)
#pragma unroll
        for (int b = 0; b < 4; ++b)
#pragma unroll
            for (int r = 0; r < 4; ++r) {
                int row = mBase + mw * 64 + f * 16 + quad * 4 + r;
                int c = nBase + nw * 64 + b * 16 + c16;
                out[(size_t)(e * T_ + row) * H_ + c] = acc[f][b][r];
            }
}

extern "C" void kernel_launch(void* const* d_in, const int* in_sizes, int n_in,
                              void* d_out, int out_size, void* d_ws, size_t ws_size,
                              hipStream_t stream) {
    const float* x = (const float*)d_in[0];
    const int* gup = (const int*)d_in[1];
    const float* gus = (const float*)d_in[2];
    const float* gug = (const float*)d_in[3];
    const int* dp = (const int*)d_in[4];
    const float* dsc = (const float*)d_in[5];
    const float* dg = (const float*)d_in[6];
    float* out = (float*)d_out;
    uint8_t* wsb = (uint8_t*)d_ws;

    const size_t per_e = (size_t)T_ * I_ * 2;                       // 8.39 MB
    const size_t wg_b = (size_t)E_ * (H_ / 8) * N1_ * 4;            // 64 MB
    const size_t wd_b = (size_t)E_ * (I_ / 8) * H_ * 4;             // 32 MB
    const size_t xh_b = (size_t)E_ * T_ * H_ * 2;                   // 32 MB
    const size_t tail_end = ws_size & ~(size_t)15;

    int mode; size_t resv;
    if (tail_end >= wg_b + wd_b + xh_b + per_e) { mode = 2; resv = wg_b + wd_b + xh_b; }
    else if (tail_end >= wg_b + wd_b + per_e)   { mode = 1; resv = wg_b + wd_b; }
    else                                        { mode = 0; resv = 0; }
    const size_t avail = tail_end - resv;
    int C = avail >= 8 * per_e ? 8 : avail >= 4 * per_e ? 4 : avail >= 2 * per_e ? 2 : 1;

    ushort_t* inter = (ushort_t*)wsb;
    unsigned* wgc = (unsigned*)(wsb + tail_end - resv);
    unsigned* wdc = (unsigned*)(wsb + tail_end - resv + wg_b);
    ushort_t* xhp = (ushort_t*)(wsb + tail_end - resv + wg_b + wd_b);
    const ushort_t* xh_arg = (mode == 2) ? (const ushort_t*)xhp : (const ushort_t*)wsb;
    const unsigned* wgc_arg = (mode >= 1) ? (const unsigned*)wgc : (const unsigned*)wsb;
    const unsigned* wdc_arg = (mode >= 1) ? (const unsigned*)wdc : (const unsigned*)wsb;

    if (mode >= 1) {
        pack_w_kernel<H_ / 8, N1_><<<2048, 256, 0, stream>>>(gup, wgc);
        pack_w_kernel<I_ / 8, H_><<<2048, 256, 0, stream>>>(dp, wdc);
    }
    if (mode == 2) pack_x_kernel<<<2048, 256, 0, stream>>>(x, xhp);

    for (int e0 = 0; e0 < E_; e0 += C) {
        dim3 g1(I_ / 64, T_ / 256, C), g2(H_ / 128, T_ / 256, C);
        switch (mode) {
            case 2:
                gemm1_kernel<2><<<g1, 512, 0, stream>>>(x, xh_arg, gup, wgc_arg, gus, gug, inter, e0);
                gemm2_kernel<1><<<g2, 512, 0, stream>>>(inter, dp, wdc_arg, dsc, dg, out, e0);
                break;
            case 1:
                gemm1_kernel<1><<<g1, 512, 0, stream>>>(x, xh_arg, gup, wgc_arg, gus, gug, inter, e0);
                gemm2_kernel<1><<<g2, 512, 0, stream>>>(inter, dp, wdc_arg, dsc, dg, out, e0);
                break;
            default:
                gemm1_kernel<0><<<g1, 512, 0, stream>>>(x, xh_arg, gup, wgc_arg, gus, gug, inter, e0);
                gemm2_kernel<0><<<g2, 512, 0, stream>>>(inter, dp, wdc_arg, dsc, dg, out, e0);
                break;
        }
    }
}

// Round 7
// 1001.557 us; speedup vs baseline: 1.6635x; 1.6635x over previous
//
#include <hip/hip_runtime.h>
#include <stdint.h>

#define E_ 8
#define H_ 2048
#define I_ 4096
#define T_ 1024
#define N1_ (2 * I_) /* 8192 */

typedef unsigned short ushort_t;
typedef _Float16 half_t;
typedef __attribute__((ext_vector_type(2))) _Float16 h2;
typedef __attribute__((ext_vector_type(8))) _Float16 f16x8;
typedef __attribute__((ext_vector_type(4))) float f32x4;

// pack two fp32 -> two f16 (RTZ) in one dword: 1 VALU op
__device__ __forceinline__ uint32_t pk2h(float a, float b) {
    auto r = __builtin_amdgcn_cvt_pkrtz(a, b);
    uint32_t u;
    __builtin_memcpy(&u, &r, 4);
    return u;
}

// per-K-step scale: fold gscale*blockscale/64 into a packed f16 pair
__device__ __forceinline__ h2 mk_ss(float sv) {
    half_t h = (half_t)(sv * 0.015625f); // /64: LUT stores value*64
    h2 r; r.x = h; r.y = h;
    return r;
}

// ---- dequant 4 packed words (1 byte each = 2 fp4 codes) -> 4 dwords of 2 scaled f16 ----
__device__ __forceinline__ uint4 dq_quad(const int wt[4], h2 ss) {
    uint32_t t0 = __builtin_amdgcn_perm((uint32_t)wt[1], (uint32_t)wt[0], 0x0C0C0400u);
    uint32_t t1 = __builtin_amdgcn_perm((uint32_t)wt[3], (uint32_t)wt[2], 0x04000C0Cu);
    uint32_t w4 = t0 | t1;
    const uint32_t T_LO = 0x56545000u; // codes 0..3 f16-hi of val*64
    const uint32_t T_HI = 0x5E5C5A58u; // codes 4..7
    uint32_t selL = w4 & 0x07070707u;
    uint32_t selH = (w4 >> 4) & 0x07070707u;
    uint32_t hiL = __builtin_amdgcn_perm(T_HI, T_LO, selL) | ((w4 & 0x08080808u) << 4);
    uint32_t hiH = __builtin_amdgcn_perm(T_HI, T_LO, selH) | (w4 & 0x80808080u);
    uint32_t p0 = __builtin_amdgcn_perm(hiH, hiL, 0x040C000Cu);
    uint32_t p1 = __builtin_amdgcn_perm(hiH, hiL, 0x050C010Cu);
    uint32_t p2 = __builtin_amdgcn_perm(hiH, hiL, 0x060C020Cu);
    uint32_t p3 = __builtin_amdgcn_perm(hiH, hiL, 0x070C030Cu);
    uint4 q;
    h2 r0 = *(h2*)&p0 * ss; __builtin_memcpy(&q.x, &r0, 4);
    h2 r1 = *(h2*)&p1 * ss; __builtin_memcpy(&q.y, &r1, 4);
    h2 r2 = *(h2*)&p2 * ss; __builtin_memcpy(&q.z, &r2, 4);
    h2 r3 = *(h2*)&p3 * ss; __builtin_memcpy(&q.w, &r3, 4);
    return q;
}

// XCD-locality swizzle (T1): consecutive HW block ids round-robin the 8 XCDs.
// Remap so each XCD owns a contiguous lex chunk of (z,y,x) => one expert's
// weights + activation panel become L2-resident per XCD (L2s are not coherent,
// so the default scatter duplicates fetches up to 8x). Bijective: total%8==0.
__device__ __forceinline__ void xcd_map(int gx, int gy, int& bx, int& by, int& bz) {
    const int total = gx * gy * (int)gridDim.z;
    const int bflat = (int)blockIdx.x + gx * ((int)blockIdx.y + gy * (int)blockIdx.z);
    const int share = total >> 3;
    const int bswz = (bflat & 7) * share + (bflat >> 3);
    bx = bswz % gx;
    const int rem = bswz / gx;
    by = rem % gy;
    bz = rem / gy;
}

// ==================== GEMM1: x(fp32) @ dequant(Wgu) + silu, pipelined ====================
// 512 thr, BM=256, tile = 64 I-cols (gate+up). 8 waves 4Mx2N.
__global__ __launch_bounds__(512, 4) void gemm1_kernel(
    const float* __restrict__ x,
    const int* __restrict__ gup,
    const float* __restrict__ gus,
    const float* __restrict__ gscale_p,
    ushort_t* __restrict__ inter,
    int e0) {
    __shared__ __align__(16) ushort_t As[2][256 * 40];
    __shared__ __align__(16) ushort_t Bs[2][128 * 40];

    const int tid = threadIdx.x;
    const int lane = tid & 63, wv = tid >> 6;
    const int quad = lane >> 4, c16 = lane & 15;
    const int mw = wv >> 1, nw = wv & 1;
    int bx, by, bz;
    xcd_map(I_ / 64, T_ / 256, bx, by, bz);
    const int zloc = bz, e = e0 + zloc;
    const int mBase = by * 256, nTile = bx;
    const float gsc = gscale_p[0];

    // B staging: kq in-wave, 16 cols per wave
    const int kq = (tid >> 4) & 3;
    const int bn = (tid & 15) | ((tid >> 6) << 4);
    const int colg = nTile * 64 + (bn & 63) + ((bn >> 6) << 12);
    const int* bptr = gup + (size_t)e * (H_ / 2) * N1_ + (size_t)(kq * 4) * N1_ + colg;
    const float* sptr = gus + (size_t)e * (H_ / 16) * N1_ + (size_t)(kq >> 1) * N1_ + colg;

    // A staging: 128 rows x 4 segs, uint4 LDS writes
    const int arow = tid >> 2, seg = tid & 3;
    const float* ap = x + (size_t)(e * T_ + mBase + arow) * H_ + seg * 8;

    f32x4 accg[4][2], accu[4][2];
    const f32x4 z4 = {0.f, 0.f, 0.f, 0.f};
#pragma unroll
    for (int f = 0; f < 4; ++f)
#pragma unroll
        for (int b = 0; b < 2; ++b) { accg[f][b] = z4; accu[f][b] = z4; }

    float4 fa[4]; int wt[4]; float sv;
    // ---- prologue: tile 0 ----
    fa[0] = *(const float4*)(ap);
    fa[1] = *(const float4*)(ap + 4);
    fa[2] = *(const float4*)(ap + (size_t)128 * H_);
    fa[3] = *(const float4*)(ap + (size_t)128 * H_ + 4);
#pragma unroll
    for (int i = 0; i < 4; ++i) wt[i] = bptr[(size_t)i * N1_];
    sv = sptr[0] * gsc;
    {
        uint4 d0, d1;
        d0.x = pk2h(fa[0].x, fa[0].y); d0.y = pk2h(fa[0].z, fa[0].w);
        d0.z = pk2h(fa[1].x, fa[1].y); d0.w = pk2h(fa[1].z, fa[1].w);
        d1.x = pk2h(fa[2].x, fa[2].y); d1.y = pk2h(fa[2].z, fa[2].w);
        d1.z = pk2h(fa[3].x, fa[3].y); d1.w = pk2h(fa[3].z, fa[3].w);
        *(uint4*)(&As[0][arow * 40 + seg * 8]) = d0;
        *(uint4*)(&As[0][(arow + 128) * 40 + seg * 8]) = d1;
        uint4 q = dq_quad(wt, mk_ss(sv));
        *(uint4*)(&Bs[0][bn * 40 + kq * 8]) = q;
    }
    __syncthreads();

    for (int kt = 0; kt < H_ / 32 - 1; ++kt) {
        const int cur = kt & 1, nxt = cur ^ 1;
        // ---- prefetch tile kt+1 into registers ----
        fa[0] = *(const float4*)(ap + (kt + 1) * 32);
        fa[1] = *(const float4*)(ap + (kt + 1) * 32 + 4);
        fa[2] = *(const float4*)(ap + (size_t)128 * H_ + (kt + 1) * 32);
        fa[3] = *(const float4*)(ap + (size_t)128 * H_ + (kt + 1) * 32 + 4);
        const int* bp = bptr + (size_t)(kt + 1) * 16 * N1_;
#pragma unroll
        for (int i = 0; i < 4; ++i) wt[i] = bp[(size_t)i * N1_];
        sv = sptr[(size_t)(kt + 1) * 2 * N1_] * gsc;

        // ---- consume current LDS tile ----
        f16x8 bg0 = *(const f16x8*)(&Bs[cur][(nw * 32 + c16) * 40 + quad * 8]);
        f16x8 bg1 = *(const f16x8*)(&Bs[cur][(nw * 32 + 16 + c16) * 40 + quad * 8]);
        f16x8 bu0 = *(const f16x8*)(&Bs[cur][(64 + nw * 32 + c16) * 40 + quad * 8]);
        f16x8 bu1 = *(const f16x8*)(&Bs[cur][(64 + nw * 32 + 16 + c16) * 40 + quad * 8]);
#pragma unroll
        for (int f = 0; f < 4; ++f) {
            f16x8 af = *(const f16x8*)(&As[cur][(mw * 64 + f * 16 + c16) * 40 + quad * 8]);
            accg[f][0] = __builtin_amdgcn_mfma_f32_16x16x32_f16(af, bg0, accg[f][0], 0, 0, 0);
            accg[f][1] = __builtin_amdgcn_mfma_f32_16x16x32_f16(af, bg1, accg[f][1], 0, 0, 0);
            accu[f][0] = __builtin_amdgcn_mfma_f32_16x16x32_f16(af, bu0, accu[f][0], 0, 0, 0);
            accu[f][1] = __builtin_amdgcn_mfma_f32_16x16x32_f16(af, bu1, accu[f][1], 0, 0, 0);
        }

        // ---- stage prefetched tile into other buffer ----
        {
            uint4 d0, d1;
            d0.x = pk2h(fa[0].x, fa[0].y); d0.y = pk2h(fa[0].z, fa[0].w);
            d0.z = pk2h(fa[1].x, fa[1].y); d0.w = pk2h(fa[1].z, fa[1].w);
            d1.x = pk2h(fa[2].x, fa[2].y); d1.y = pk2h(fa[2].z, fa[2].w);
            d1.z = pk2h(fa[3].x, fa[3].y); d1.w = pk2h(fa[3].z, fa[3].w);
            *(uint4*)(&As[nxt][arow * 40 + seg * 8]) = d0;
            *(uint4*)(&As[nxt][(arow + 128) * 40 + seg * 8]) = d1;
            uint4 q = dq_quad(wt, mk_ss(sv));
            *(uint4*)(&Bs[nxt][bn * 40 + kq * 8]) = q;
        }
        __syncthreads();
    }

    // ---- last tile ----
    {
        const int cur = (H_ / 32 - 1) & 1;
        f16x8 bg0 = *(const f16x8*)(&Bs[cur][(nw * 32 + c16) * 40 + quad * 8]);
        f16x8 bg1 = *(const f16x8*)(&Bs[cur][(nw * 32 + 16 + c16) * 40 + quad * 8]);
        f16x8 bu0 = *(const f16x8*)(&Bs[cur][(64 + nw * 32 + c16) * 40 + quad * 8]);
        f16x8 bu1 = *(const f16x8*)(&Bs[cur][(64 + nw * 32 + 16 + c16) * 40 + quad * 8]);
#pragma unroll
        for (int f = 0; f < 4; ++f) {
            f16x8 af = *(const f16x8*)(&As[cur][(mw * 64 + f * 16 + c16) * 40 + quad * 8]);
            accg[f][0] = __builtin_amdgcn_mfma_f32_16x16x32_f16(af, bg0, accg[f][0], 0, 0, 0);
            accg[f][1] = __builtin_amdgcn_mfma_f32_16x16x32_f16(af, bg1, accg[f][1], 0, 0, 0);
            accu[f][0] = __builtin_amdgcn_mfma_f32_16x16x32_f16(af, bu0, accu[f][0], 0, 0, 0);
            accu[f][1] = __builtin_amdgcn_mfma_f32_16x16x32_f16(af, bu1, accu[f][1], 0, 0, 0);
        }
    }

    // epilogue: inter = up * silu(gate), stored as f16
    ushort_t* ip = inter + (size_t)zloc * T_ * I_;
#pragma unroll
    for (int f = 0; f < 4; ++f)
#pragma unroll
        for (int b = 0; b < 2; ++b)
#pragma unroll
            for (int r = 0; r < 4; ++r) {
                int row = mBase + mw * 64 + f * 16 + quad * 4 + r;
                int col = nTile * 64 + nw * 32 + b * 16 + c16;
                float g = accg[f][b][r];
                float u = accu[f][b][r];
                float v = u * g / (1.f + __expf(-g));
                half_t hv = (half_t)v;
                ushort_t hu;
                __builtin_memcpy(&hu, &hv, 2);
                ip[(size_t)row * I_ + col] = hu;
            }
}

// ==================== GEMM2: inter(f16) @ dequant(Wd) -> fp32, pipelined ====================
// 512 thr, BM=256, BN=128. 8 waves 4Mx2N.
__global__ __launch_bounds__(512, 4) void gemm2_kernel(
    const ushort_t* __restrict__ inter,
    const int* __restrict__ dp,
    const float* __restrict__ dsc,
    const float* __restrict__ gscale_p,
    float* __restrict__ out,
    int e0) {
    __shared__ __align__(16) ushort_t As[2][256 * 40];
    __shared__ __align__(16) ushort_t Bs[2][128 * 40];

    const int tid = threadIdx.x;
    const int lane = tid & 63, wv = tid >> 6;
    const int quad = lane >> 4, c16 = lane & 15;
    const int mw = wv >> 1, nw = wv & 1;
    int bx, by, bz;
    xcd_map(H_ / 128, T_ / 256, bx, by, bz);
    const int zloc = bz, e = e0 + zloc;
    const int mBase = by * 256, nBase = bx * 128;
    const float gsc = gscale_p[0];

    const int kq = (tid >> 4) & 3;
    const int bn = (tid & 15) | ((tid >> 6) << 4);
    const int col = nBase + bn;
    const int* bptr = dp + (size_t)e * (I_ / 2) * H_ + (size_t)(kq * 4) * H_ + col;
    const float* sptr = dsc + (size_t)e * (I_ / 16) * H_ + (size_t)(kq >> 1) * H_ + col;

    const int arow = tid >> 2, seg = tid & 3;
    const ushort_t* ap = inter + (size_t)(zloc * T_ + mBase + arow) * I_ + seg * 8;

    f32x4 acc[4][4];
    const f32x4 z4 = {0.f, 0.f, 0.f, 0.f};
#pragma unroll
    for (int f = 0; f < 4; ++f)
#pragma unroll
        for (int b = 0; b < 4; ++b) acc[f][b] = z4;

    uint4 va[2]; int wt[4]; float sv;
    // ---- prologue: tile 0 ----
#pragma unroll
    for (int p = 0; p < 2; ++p) va[p] = *(const uint4*)(ap + (size_t)(p * 128) * I_);
#pragma unroll
    for (int i = 0; i < 4; ++i) wt[i] = bptr[(size_t)i * H_];
    sv = sptr[0] * gsc;
    {
#pragma unroll
        for (int p = 0; p < 2; ++p)
            *(uint4*)(&As[0][(arow + p * 128) * 40 + seg * 8]) = va[p];
        uint4 q = dq_quad(wt, mk_ss(sv));
        *(uint4*)(&Bs[0][bn * 40 + kq * 8]) = q;
    }
    __syncthreads();

    for (int kt = 0; kt < I_ / 32 - 1; ++kt) {
        const int cur = kt & 1, nxt = cur ^ 1;
        // ---- prefetch tile kt+1 ----
#pragma unroll
        for (int p = 0; p < 2; ++p)
            va[p] = *(const uint4*)(ap + (size_t)(p * 128) * I_ + (kt + 1) * 32);
        const int* bp = bptr + (size_t)(kt + 1) * 16 * H_;
#pragma unroll
        for (int i = 0; i < 4; ++i) wt[i] = bp[(size_t)i * H_];
        sv = sptr[(size_t)(kt + 1) * 2 * H_] * gsc;

        // ---- consume current ----
        f16x8 bfr[4];
#pragma unroll
        for (int b = 0; b < 4; ++b)
            bfr[b] = *(const f16x8*)(&Bs[cur][(nw * 64 + b * 16 + c16) * 40 + quad * 8]);
#pragma unroll
        for (int f = 0; f < 4; ++f) {
            f16x8 af = *(const f16x8*)(&As[cur][(mw * 64 + f * 16 + c16) * 40 + quad * 8]);
#pragma unroll
            for (int b = 0; b < 4; ++b)
                acc[f][b] = __builtin_amdgcn_mfma_f32_16x16x32_f16(af, bfr[b], acc[f][b], 0, 0, 0);
        }

        // ---- stage next ----
#pragma unroll
        for (int p = 0; p < 2; ++p)
            *(uint4*)(&As[nxt][(arow + p * 128) * 40 + seg * 8]) = va[p];
        uint4 q = dq_quad(wt, mk_ss(sv));
        *(uint4*)(&Bs[nxt][bn * 40 + kq * 8]) = q;
        __syncthreads();
    }

    // ---- last tile ----
    {
        const int cur = (I_ / 32 - 1) & 1;
        f16x8 bfr[4];
#pragma unroll
        for (int b = 0; b < 4; ++b)
            bfr[b] = *(const f16x8*)(&Bs[cur][(nw * 64 + b * 16 + c16) * 40 + quad * 8]);
#pragma unroll
        for (int f = 0; f < 4; ++f) {
            f16x8 af = *(const f16x8*)(&As[cur][(mw * 64 + f * 16 + c16) * 40 + quad * 8]);
#pragma unroll
            for (int b = 0; b < 4; ++b)
                acc[f][b] = __builtin_amdgcn_mfma_f32_16x16x32_f16(af, bfr[b], acc[f][b], 0, 0, 0);
        }
    }

#pragma unroll
    for (int f = 0; f < 4; ++f)
#pragma unroll
        for (int b = 0; b < 4; ++b)
#pragma unroll
            for (int r = 0; r < 4; ++r) {
                int row = mBase + mw * 64 + f * 16 + quad * 4 + r;
                int c = nBase + nw * 64 + b * 16 + c16;
                out[(size_t)(e * T_ + row) * H_ + c] = acc[f][b][r];
            }
}

extern "C" void kernel_launch(void* const* d_in, const int* in_sizes, int n_in,
                              void* d_out, int out_size, void* d_ws, size_t ws_size,
                              hipStream_t stream) {
    const float* x = (const float*)d_in[0];
    const int* gup = (const int*)d_in[1];
    const float* gus = (const float*)d_in[2];
    const float* gug = (const float*)d_in[3];
    const int* dp = (const int*)d_in[4];
    const float* dsc = (const float*)d_in[5];
    const float* dg = (const float*)d_in[6];
    float* out = (float*)d_out;
    ushort_t* inter = (ushort_t*)d_ws;

    const size_t per_e = (size_t)T_ * I_ * 2;
    int C = 8;
    if (ws_size < 8 * per_e) C = (ws_size >= 4 * per_e) ? 4 : (ws_size >= 2 * per_e) ? 2 : 1;

    for (int e0 = 0; e0 < E_; e0 += C) {
        gemm1_kernel<<<dim3(I_ / 64, T_ / 256, C), 512, 0, stream>>>(x, gup, gus, gug, inter, e0);
        gemm2_kernel<<<dim3(H_ / 128, T_ / 256, C), 512, 0, stream>>>(inter, dp, dsc, dg, out, e0);
    }
}

// Round 10
// 994.995 us; speedup vs baseline: 1.6745x; 1.0066x over previous
//
#include <hip/hip_runtime.h>
#include <stdint.h>

#define E_ 8
#define H_ 2048
#define I_ 4096
#define T_ 1024
#define N1_ (2 * I_) /* 8192 */

typedef unsigned short ushort_t;
typedef _Float16 half_t;
typedef __attribute__((ext_vector_type(2))) _Float16 h2;
typedef __attribute__((ext_vector_type(8))) _Float16 f16x8;
typedef __attribute__((ext_vector_type(4))) float f32x4;

// async 16B global->LDS copy (no VGPR round-trip). LDS dest = wave-uniform
// base + lane*16 (hardware); src is per-lane. Drained by __syncthreads's
// compiler-emitted vmcnt(0) (m97 pattern).
__device__ __forceinline__ void cp16_async(const void* g, void* l) {
    __builtin_amdgcn_global_load_lds(
        (const __attribute__((address_space(1))) unsigned*)g,
        (__attribute__((address_space(3))) unsigned*)l, 16, 0, 0);
}

// pack two fp32 -> two f16 (RTZ) in one dword: 1 VALU op
__device__ __forceinline__ uint32_t pk2h(float a, float b) {
    auto r = __builtin_amdgcn_cvt_pkrtz(a, b);
    uint32_t u;
    __builtin_memcpy(&u, &r, 4);
    return u;
}

// per-K-step scale: fold gscale*blockscale/64 into a packed f16 pair
__device__ __forceinline__ h2 mk_ss(float sv) {
    half_t h = (half_t)(sv * 0.015625f); // /64: LUT stores value*64
    h2 r; r.x = h; r.y = h;
    return r;
}

// ---- dequant 4 packed words (1 byte each = 2 fp4 codes) -> 4 dwords of 2 scaled f16 ----
__device__ __forceinline__ uint4 dq_quad(const int wt[4], h2 ss) {
    uint32_t t0 = __builtin_amdgcn_perm((uint32_t)wt[1], (uint32_t)wt[0], 0x0C0C0400u);
    uint32_t t1 = __builtin_amdgcn_perm((uint32_t)wt[3], (uint32_t)wt[2], 0x04000C0Cu);
    uint32_t w4 = t0 | t1;
    const uint32_t T_LO = 0x56545000u; // codes 0..3 f16-hi of val*64
    const uint32_t T_HI = 0x5E5C5A58u; // codes 4..7
    uint32_t selL = w4 & 0x07070707u;
    uint32_t selH = (w4 >> 4) & 0x07070707u;
    uint32_t hiL = __builtin_amdgcn_perm(T_HI, T_LO, selL) | ((w4 & 0x08080808u) << 4);
    uint32_t hiH = __builtin_amdgcn_perm(T_HI, T_LO, selH) | (w4 & 0x80808080u);
    uint32_t p0 = __builtin_amdgcn_perm(hiH, hiL, 0x040C000Cu);
    uint32_t p1 = __builtin_amdgcn_perm(hiH, hiL, 0x050C010Cu);
    uint32_t p2 = __builtin_amdgcn_perm(hiH, hiL, 0x060C020Cu);
    uint32_t p3 = __builtin_amdgcn_perm(hiH, hiL, 0x070C030Cu);
    uint4 q;
    h2 r0 = *(h2*)&p0 * ss; __builtin_memcpy(&q.x, &r0, 4);
    h2 r1 = *(h2*)&p1 * ss; __builtin_memcpy(&q.y, &r1, 4);
    h2 r2 = *(h2*)&p2 * ss; __builtin_memcpy(&q.z, &r2, 4);
    h2 r3 = *(h2*)&p3 * ss; __builtin_memcpy(&q.w, &r3, 4);
    return q;
}

// ==================== GEMM1: x(fp32) @ dequant(Wgu) + silu, pipelined ====================
// (verified round-5 kernel, unchanged: 447 us, Mfma 27.4 / VALU 33)
__global__ __launch_bounds__(512, 4) void gemm1_kernel(
    const float* __restrict__ x,
    const int* __restrict__ gup,
    const float* __restrict__ gus,
    const float* __restrict__ gscale_p,
    ushort_t* __restrict__ inter,
    int e0) {
    __shared__ __align__(16) ushort_t As[2][256 * 40];
    __shared__ __align__(16) ushort_t Bs[2][128 * 40];

    const int tid = threadIdx.x;
    const int lane = tid & 63, wv = tid >> 6;
    const int quad = lane >> 4, c16 = lane & 15;
    const int mw = wv >> 1, nw = wv & 1;
    const int zloc = blockIdx.z, e = e0 + zloc;
    const int mBase = blockIdx.y * 256, nTile = blockIdx.x;
    const float gsc = gscale_p[0];

    const int kq = (tid >> 4) & 3;
    const int bn = (tid & 15) | ((tid >> 6) << 4);
    const int colg = nTile * 64 + (bn & 63) + ((bn >> 6) << 12);
    const int* bptr = gup + (size_t)e * (H_ / 2) * N1_ + (size_t)(kq * 4) * N1_ + colg;
    const float* sptr = gus + (size_t)e * (H_ / 16) * N1_ + (size_t)(kq >> 1) * N1_ + colg;

    const int arow = tid >> 2, seg = tid & 3;
    const float* ap = x + (size_t)(e * T_ + mBase + arow) * H_ + seg * 8;

    f32x4 accg[4][2], accu[4][2];
    const f32x4 z4 = {0.f, 0.f, 0.f, 0.f};
#pragma unroll
    for (int f = 0; f < 4; ++f)
#pragma unroll
        for (int b = 0; b < 2; ++b) { accg[f][b] = z4; accu[f][b] = z4; }

    float4 fa[4]; int wt[4]; float sv;
    fa[0] = *(const float4*)(ap);
    fa[1] = *(const float4*)(ap + 4);
    fa[2] = *(const float4*)(ap + (size_t)128 * H_);
    fa[3] = *(const float4*)(ap + (size_t)128 * H_ + 4);
#pragma unroll
    for (int i = 0; i < 4; ++i) wt[i] = bptr[(size_t)i * N1_];
    sv = sptr[0] * gsc;
    {
        uint4 d0, d1;
        d0.x = pk2h(fa[0].x, fa[0].y); d0.y = pk2h(fa[0].z, fa[0].w);
        d0.z = pk2h(fa[1].x, fa[1].y); d0.w = pk2h(fa[1].z, fa[1].w);
        d1.x = pk2h(fa[2].x, fa[2].y); d1.y = pk2h(fa[2].z, fa[2].w);
        d1.z = pk2h(fa[3].x, fa[3].y); d1.w = pk2h(fa[3].z, fa[3].w);
        *(uint4*)(&As[0][arow * 40 + seg * 8]) = d0;
        *(uint4*)(&As[0][(arow + 128) * 40 + seg * 8]) = d1;
        uint4 q = dq_quad(wt, mk_ss(sv));
        *(uint4*)(&Bs[0][bn * 40 + kq * 8]) = q;
    }
    __syncthreads();

    for (int kt = 0; kt < H_ / 32 - 1; ++kt) {
        const int cur = kt & 1, nxt = cur ^ 1;
        fa[0] = *(const float4*)(ap + (kt + 1) * 32);
        fa[1] = *(const float4*)(ap + (kt + 1) * 32 + 4);
        fa[2] = *(const float4*)(ap + (size_t)128 * H_ + (kt + 1) * 32);
        fa[3] = *(const float4*)(ap + (size_t)128 * H_ + (kt + 1) * 32 + 4);
        const int* bp = bptr + (size_t)(kt + 1) * 16 * N1_;
#pragma unroll
        for (int i = 0; i < 4; ++i) wt[i] = bp[(size_t)i * N1_];
        sv = sptr[(size_t)(kt + 1) * 2 * N1_] * gsc;

        f16x8 bg0 = *(const f16x8*)(&Bs[cur][(nw * 32 + c16) * 40 + quad * 8]);
        f16x8 bg1 = *(const f16x8*)(&Bs[cur][(nw * 32 + 16 + c16) * 40 + quad * 8]);
        f16x8 bu0 = *(const f16x8*)(&Bs[cur][(64 + nw * 32 + c16) * 40 + quad * 8]);
        f16x8 bu1 = *(const f16x8*)(&Bs[cur][(64 + nw * 32 + 16 + c16) * 40 + quad * 8]);
#pragma unroll
        for (int f = 0; f < 4; ++f) {
            f16x8 af = *(const f16x8*)(&As[cur][(mw * 64 + f * 16 + c16) * 40 + quad * 8]);
            accg[f][0] = __builtin_amdgcn_mfma_f32_16x16x32_f16(af, bg0, accg[f][0], 0, 0, 0);
            accg[f][1] = __builtin_amdgcn_mfma_f32_16x16x32_f16(af, bg1, accg[f][1], 0, 0, 0);
            accu[f][0] = __builtin_amdgcn_mfma_f32_16x16x32_f16(af, bu0, accu[f][0], 0, 0, 0);
            accu[f][1] = __builtin_amdgcn_mfma_f32_16x16x32_f16(af, bu1, accu[f][1], 0, 0, 0);
        }

        {
            uint4 d0, d1;
            d0.x = pk2h(fa[0].x, fa[0].y); d0.y = pk2h(fa[0].z, fa[0].w);
            d0.z = pk2h(fa[1].x, fa[1].y); d0.w = pk2h(fa[1].z, fa[1].w);
            d1.x = pk2h(fa[2].x, fa[2].y); d1.y = pk2h(fa[2].z, fa[2].w);
            d1.z = pk2h(fa[3].x, fa[3].y); d1.w = pk2h(fa[3].z, fa[3].w);
            *(uint4*)(&As[nxt][arow * 40 + seg * 8]) = d0;
            *(uint4*)(&As[nxt][(arow + 128) * 40 + seg * 8]) = d1;
            uint4 q = dq_quad(wt, mk_ss(sv));
            *(uint4*)(&Bs[nxt][bn * 40 + kq * 8]) = q;
        }
        __syncthreads();
    }

    {
        const int cur = (H_ / 32 - 1) & 1;
        f16x8 bg0 = *(const f16x8*)(&Bs[cur][(nw * 32 + c16) * 40 + quad * 8]);
        f16x8 bg1 = *(const f16x8*)(&Bs[cur][(nw * 32 + 16 + c16) * 40 + quad * 8]);
        f16x8 bu0 = *(const f16x8*)(&Bs[cur][(64 + nw * 32 + c16) * 40 + quad * 8]);
        f16x8 bu1 = *(const f16x8*)(&Bs[cur][(64 + nw * 32 + 16 + c16) * 40 + quad * 8]);
#pragma unroll
        for (int f = 0; f < 4; ++f) {
            f16x8 af = *(const f16x8*)(&As[cur][(mw * 64 + f * 16 + c16) * 40 + quad * 8]);
            accg[f][0] = __builtin_amdgcn_mfma_f32_16x16x32_f16(af, bg0, accg[f][0], 0, 0, 0);
            accg[f][1] = __builtin_amdgcn_mfma_f32_16x16x32_f16(af, bg1, accg[f][1], 0, 0, 0);
            accu[f][0] = __builtin_amdgcn_mfma_f32_16x16x32_f16(af, bu0, accu[f][0], 0, 0, 0);
            accu[f][1] = __builtin_amdgcn_mfma_f32_16x16x32_f16(af, bu1, accu[f][1], 0, 0, 0);
        }
    }

    ushort_t* ip = inter + (size_t)zloc * T_ * I_;
#pragma unroll
    for (int f = 0; f < 4; ++f)
#pragma unroll
        for (int b = 0; b < 2; ++b)
#pragma unroll
            for (int r = 0; r < 4; ++r) {
                int row = mBase + mw * 64 + f * 16 + quad * 4 + r;
                int col = nTile * 64 + nw * 32 + b * 16 + c16;
                float g = accg[f][b][r];
                float u = accu[f][b][r];
                float v = u * g / (1.f + __expf(-g));
                half_t hv = (half_t)v;
                ushort_t hu;
                __builtin_memcpy(&hu, &hv, 2);
                ip[(size_t)row * I_ + col] = hu;
            }
}

// ==================== GEMM2: inter(f16) @ dequant(Wd) -> fp32 ====================
// A-staging via async global_load_lds (pure f16 copy, linear [256][32] tile,
// issued at loop top -> overlaps the whole MFMA phase). B stays reg-staged
// (dequant needs VALU).
__global__ __launch_bounds__(512, 4) void gemm2_kernel(
    const ushort_t* __restrict__ inter,
    const int* __restrict__ dp,
    const float* __restrict__ dsc,
    const float* __restrict__ gscale_p,
    float* __restrict__ out,
    int e0) {
    __shared__ __align__(16) ushort_t As[2][256 * 32]; // linear 64B rows (gload_lds needs no pad)
    __shared__ __align__(16) ushort_t Bs[2][128 * 40];

    const int tid = threadIdx.x;
    const int lane = tid & 63, wv = tid >> 6;
    const int quad = lane >> 4, c16 = lane & 15;
    const int mw = wv >> 1, nw = wv & 1;
    const int zloc = blockIdx.z, e = e0 + zloc;
    const int mBase = blockIdx.y * 256, nBase = blockIdx.x * 128;
    const float gsc = gscale_p[0];

    const int kq = (tid >> 4) & 3;
    const int bn = (tid & 15) | ((tid >> 6) << 4);
    const int col = nBase + bn;
    const int* bptr = dp + (size_t)e * (I_ / 2) * H_ + (size_t)(kq * 4) * H_ + col;
    const float* sptr = dsc + (size_t)e * (I_ / 16) * H_ + (size_t)(kq >> 1) * H_ + col;

    // async-A: wave wv copies rows [wv*16 .. wv*16+15] (call 0) and +128 (call 1).
    // lane l covers row wv*16 + l/4, 16B chunk l%4 -> LDS linear base + l*16.
    const ushort_t* srcA = inter + (size_t)(zloc * T_ + mBase + wv * 16 + (lane >> 2)) * I_ + (lane & 3) * 8;
    const size_t srcA2off = (size_t)128 * I_;
    const int ldsAw = wv * 16 * 32; // ushort index of wave's dest base (call 0)

    f32x4 acc[4][4];
    const f32x4 z4 = {0.f, 0.f, 0.f, 0.f};
#pragma unroll
    for (int f = 0; f < 4; ++f)
#pragma unroll
        for (int b = 0; b < 4; ++b) acc[f][b] = z4;

    int wt[4]; float sv;
    // ---- prologue: tile 0 ----
    cp16_async(srcA, &As[0][ldsAw]);
    cp16_async(srcA + srcA2off, &As[0][128 * 32 + ldsAw]);
#pragma unroll
    for (int i = 0; i < 4; ++i) wt[i] = bptr[(size_t)i * H_];
    sv = sptr[0] * gsc;
    {
        uint4 q = dq_quad(wt, mk_ss(sv));
        *(uint4*)(&Bs[0][bn * 40 + kq * 8]) = q;
    }
    __syncthreads(); // drains vmcnt (gload_lds) + lgkm (ds_write)

    for (int kt = 0; kt < I_ / 32 - 1; ++kt) {
        const int cur = kt & 1, nxt = cur ^ 1;
        // ---- issue async A-copy for tile kt+1 (overlaps MFMA below) ----
        cp16_async(srcA + (size_t)(kt + 1) * 32, &As[nxt][ldsAw]);
        cp16_async(srcA + srcA2off + (size_t)(kt + 1) * 32, &As[nxt][128 * 32 + ldsAw]);
        // ---- B reg-prefetch tile kt+1 ----
        const int* bp = bptr + (size_t)(kt + 1) * 16 * H_;
#pragma unroll
        for (int i = 0; i < 4; ++i) wt[i] = bp[(size_t)i * H_];
        sv = sptr[(size_t)(kt + 1) * 2 * H_] * gsc;

        // ---- consume current ----
        f16x8 bfr[4];
#pragma unroll
        for (int b = 0; b < 4; ++b)
            bfr[b] = *(const f16x8*)(&Bs[cur][(nw * 64 + b * 16 + c16) * 40 + quad * 8]);
#pragma unroll
        for (int f = 0; f < 4; ++f) {
            f16x8 af = *(const f16x8*)(&As[cur][(mw * 64 + f * 16 + c16) * 32 + quad * 8]);
#pragma unroll
            for (int b = 0; b < 4; ++b)
                acc[f][b] = __builtin_amdgcn_mfma_f32_16x16x32_f16(af, bfr[b], acc[f][b], 0, 0, 0);
        }

        // ---- stage next B ----
        uint4 q = dq_quad(wt, mk_ss(sv));
        *(uint4*)(&Bs[nxt][bn * 40 + kq * 8]) = q;
        __syncthreads();
    }

    // ---- last tile ----
    {
        const int cur = (I_ / 32 - 1) & 1;
        f16x8 bfr[4];
#pragma unroll
        for (int b = 0; b < 4; ++b)
            bfr[b] = *(const f16x8*)(&Bs[cur][(nw * 64 + b * 16 + c16) * 40 + quad * 8]);
#pragma unroll
        for (int f = 0; f < 4; ++f) {
            f16x8 af = *(const f16x8*)(&As[cur][(mw * 64 + f * 16 + c16) * 32 + quad * 8]);
#pragma unroll
            for (int b = 0; b < 4; ++b)
                acc[f][b] = __builtin_amdgcn_mfma_f32_16x16x32_f16(af, bfr[b], acc[f][b], 0, 0, 0);
        }
    }

#pragma unroll
    for (int f = 0; f < 4; ++f)
#pragma unroll
        for (int b = 0; b < 4; ++b)
#pragma unroll
            for (int r = 0; r < 4; ++r) {
                int row = mBase + mw * 64 + f * 16 + quad * 4 + r;
                int c = nBase + nw * 64 + b * 16 + c16;
                out[(size_t)(e * T_ + row) * H_ + c] = acc[f][b][r];
            }
}

extern "C" void kernel_launch(void* const* d_in, const int* in_sizes, int n_in,
                              void* d_out, int out_size, void* d_ws, size_t ws_size,
                              hipStream_t stream) {
    const float* x = (const float*)d_in[0];
    const int* gup = (const int*)d_in[1];
    const float* gus = (const float*)d_in[2];
    const float* gug = (const float*)d_in[3];
    const int* dp = (const int*)d_in[4];
    const float* dsc = (const float*)d_in[5];
    const float* dg = (const float*)d_in[6];
    float* out = (float*)d_out;
    ushort_t* inter = (ushort_t*)d_ws;

    const size_t per_e = (size_t)T_ * I_ * 2;
    int C = 8;
    if (ws_size < 8 * per_e) C = (ws_size >= 4 * per_e) ? 4 : (ws_size >= 2 * per_e) ? 2 : 1;

    for (int e0 = 0; e0 < E_; e0 += C) {
        gemm1_kernel<<<dim3(I_ / 64, T_ / 256, C), 512, 0, stream>>>(x, gup, gus, gug, inter, e0);
        gemm2_kernel<<<dim3(H_ / 128, T_ / 256, C), 512, 0, stream>>>(inter, dp, dsc, dg, out, e0);
    }
}

// Round 12
// 990.098 us; speedup vs baseline: 1.6828x; 1.0049x over previous
//
#include <hip/hip_runtime.h>
#include <stdint.h>

#define E_ 8
#define H_ 2048
#define I_ 4096
#define T_ 1024
#define N1_ (2 * I_) /* 8192 */

typedef unsigned short ushort_t;
typedef _Float16 half_t;
typedef __attribute__((ext_vector_type(2))) _Float16 h2;
typedef __attribute__((ext_vector_type(8))) _Float16 f16x8;
typedef __attribute__((ext_vector_type(4))) float f32x4;

// async 16B global->LDS copy (no VGPR round-trip). LDS dest = wave-uniform
// base + lane*16 (hardware); src is per-lane. Drained by __syncthreads's
// compiler-emitted vmcnt(0) (m97 pattern).
__device__ __forceinline__ void cp16_async(const void* g, void* l) {
    __builtin_amdgcn_global_load_lds(
        (const __attribute__((address_space(1))) unsigned*)g,
        (__attribute__((address_space(3))) unsigned*)l, 16, 0, 0);
}

// pack two fp32 -> two f16 (RTZ) in one dword: 1 VALU op
__device__ __forceinline__ uint32_t pk2h(float a, float b) {
    auto r = __builtin_amdgcn_cvt_pkrtz(a, b);
    uint32_t u;
    __builtin_memcpy(&u, &r, 4);
    return u;
}

// per-K-step scale: fold gscale*blockscale/64 into a packed f16 pair
__device__ __forceinline__ h2 mk_ss(float sv) {
    half_t h = (half_t)(sv * 0.015625f); // /64: LUT stores value*64
    h2 r; r.x = h; r.y = h;
    return r;
}

// ---- dequant 4 packed words (1 byte each = 2 fp4 codes) -> 4 dwords of 2 scaled f16 ----
__device__ __forceinline__ uint4 dq_quad(const int wt[4], h2 ss) {
    uint32_t t0 = __builtin_amdgcn_perm((uint32_t)wt[1], (uint32_t)wt[0], 0x0C0C0400u);
    uint32_t t1 = __builtin_amdgcn_perm((uint32_t)wt[3], (uint32_t)wt[2], 0x04000C0Cu);
    uint32_t w4 = t0 | t1;
    const uint32_t T_LO = 0x56545000u; // codes 0..3 f16-hi of val*64
    const uint32_t T_HI = 0x5E5C5A58u; // codes 4..7
    uint32_t selL = w4 & 0x07070707u;
    uint32_t selH = (w4 >> 4) & 0x07070707u;
    uint32_t hiL = __builtin_amdgcn_perm(T_HI, T_LO, selL) | ((w4 & 0x08080808u) << 4);
    uint32_t hiH = __builtin_amdgcn_perm(T_HI, T_LO, selH) | (w4 & 0x80808080u);
    uint32_t p0 = __builtin_amdgcn_perm(hiH, hiL, 0x040C000Cu);
    uint32_t p1 = __builtin_amdgcn_perm(hiH, hiL, 0x050C010Cu);
    uint32_t p2 = __builtin_amdgcn_perm(hiH, hiL, 0x060C020Cu);
    uint32_t p3 = __builtin_amdgcn_perm(hiH, hiL, 0x070C030Cu);
    uint4 q;
    h2 r0 = *(h2*)&p0 * ss; __builtin_memcpy(&q.x, &r0, 4);
    h2 r1 = *(h2*)&p1 * ss; __builtin_memcpy(&q.y, &r1, 4);
    h2 r2 = *(h2*)&p2 * ss; __builtin_memcpy(&q.z, &r2, 4);
    h2 r3 = *(h2*)&p3 * ss; __builtin_memcpy(&q.w, &r3, 4);
    return q;
}

// ==================== GEMM1: x(fp32) @ dequant(Wgu) + silu, pipelined ====================
// (verified round-5 kernel, unchanged: 447 us, Mfma 27.9 / VALU 33.9)
__global__ __launch_bounds__(512, 4) void gemm1_kernel(
    const float* __restrict__ x,
    const int* __restrict__ gup,
    const float* __restrict__ gus,
    const float* __restrict__ gscale_p,
    ushort_t* __restrict__ inter,
    int e0) {
    __shared__ __align__(16) ushort_t As[2][256 * 40];
    __shared__ __align__(16) ushort_t Bs[2][128 * 40];

    const int tid = threadIdx.x;
    const int lane = tid & 63, wv = tid >> 6;
    const int quad = lane >> 4, c16 = lane & 15;
    const int mw = wv >> 1, nw = wv & 1;
    const int zloc = blockIdx.z, e = e0 + zloc;
    const int mBase = blockIdx.y * 256, nTile = blockIdx.x;
    const float gsc = gscale_p[0];

    const int kq = (tid >> 4) & 3;
    const int bn = (tid & 15) | ((tid >> 6) << 4);
    const int colg = nTile * 64 + (bn & 63) + ((bn >> 6) << 12);
    const int* bptr = gup + (size_t)e * (H_ / 2) * N1_ + (size_t)(kq * 4) * N1_ + colg;
    const float* sptr = gus + (size_t)e * (H_ / 16) * N1_ + (size_t)(kq >> 1) * N1_ + colg;

    const int arow = tid >> 2, seg = tid & 3;
    const float* ap = x + (size_t)(e * T_ + mBase + arow) * H_ + seg * 8;

    f32x4 accg[4][2], accu[4][2];
    const f32x4 z4 = {0.f, 0.f, 0.f, 0.f};
#pragma unroll
    for (int f = 0; f < 4; ++f)
#pragma unroll
        for (int b = 0; b < 2; ++b) { accg[f][b] = z4; accu[f][b] = z4; }

    float4 fa[4]; int wt[4]; float sv;
    fa[0] = *(const float4*)(ap);
    fa[1] = *(const float4*)(ap + 4);
    fa[2] = *(const float4*)(ap + (size_t)128 * H_);
    fa[3] = *(const float4*)(ap + (size_t)128 * H_ + 4);
#pragma unroll
    for (int i = 0; i < 4; ++i) wt[i] = bptr[(size_t)i * N1_];
    sv = sptr[0] * gsc;
    {
        uint4 d0, d1;
        d0.x = pk2h(fa[0].x, fa[0].y); d0.y = pk2h(fa[0].z, fa[0].w);
        d0.z = pk2h(fa[1].x, fa[1].y); d0.w = pk2h(fa[1].z, fa[1].w);
        d1.x = pk2h(fa[2].x, fa[2].y); d1.y = pk2h(fa[2].z, fa[2].w);
        d1.z = pk2h(fa[3].x, fa[3].y); d1.w = pk2h(fa[3].z, fa[3].w);
        *(uint4*)(&As[0][arow * 40 + seg * 8]) = d0;
        *(uint4*)(&As[0][(arow + 128) * 40 + seg * 8]) = d1;
        uint4 q = dq_quad(wt, mk_ss(sv));
        *(uint4*)(&Bs[0][bn * 40 + kq * 8]) = q;
    }
    __syncthreads();

    for (int kt = 0; kt < H_ / 32 - 1; ++kt) {
        const int cur = kt & 1, nxt = cur ^ 1;
        fa[0] = *(const float4*)(ap + (kt + 1) * 32);
        fa[1] = *(const float4*)(ap + (kt + 1) * 32 + 4);
        fa[2] = *(const float4*)(ap + (size_t)128 * H_ + (kt + 1) * 32);
        fa[3] = *(const float4*)(ap + (size_t)128 * H_ + (kt + 1) * 32 + 4);
        const int* bp = bptr + (size_t)(kt + 1) * 16 * N1_;
#pragma unroll
        for (int i = 0; i < 4; ++i) wt[i] = bp[(size_t)i * N1_];
        sv = sptr[(size_t)(kt + 1) * 2 * N1_] * gsc;

        f16x8 bg0 = *(const f16x8*)(&Bs[cur][(nw * 32 + c16) * 40 + quad * 8]);
        f16x8 bg1 = *(const f16x8*)(&Bs[cur][(nw * 32 + 16 + c16) * 40 + quad * 8]);
        f16x8 bu0 = *(const f16x8*)(&Bs[cur][(64 + nw * 32 + c16) * 40 + quad * 8]);
        f16x8 bu1 = *(const f16x8*)(&Bs[cur][(64 + nw * 32 + 16 + c16) * 40 + quad * 8]);
#pragma unroll
        for (int f = 0; f < 4; ++f) {
            f16x8 af = *(const f16x8*)(&As[cur][(mw * 64 + f * 16 + c16) * 40 + quad * 8]);
            accg[f][0] = __builtin_amdgcn_mfma_f32_16x16x32_f16(af, bg0, accg[f][0], 0, 0, 0);
            accg[f][1] = __builtin_amdgcn_mfma_f32_16x16x32_f16(af, bg1, accg[f][1], 0, 0, 0);
            accu[f][0] = __builtin_amdgcn_mfma_f32_16x16x32_f16(af, bu0, accu[f][0], 0, 0, 0);
            accu[f][1] = __builtin_amdgcn_mfma_f32_16x16x32_f16(af, bu1, accu[f][1], 0, 0, 0);
        }

        {
            uint4 d0, d1;
            d0.x = pk2h(fa[0].x, fa[0].y); d0.y = pk2h(fa[0].z, fa[0].w);
            d0.z = pk2h(fa[1].x, fa[1].y); d0.w = pk2h(fa[1].z, fa[1].w);
            d1.x = pk2h(fa[2].x, fa[2].y); d1.y = pk2h(fa[2].z, fa[2].w);
            d1.z = pk2h(fa[3].x, fa[3].y); d1.w = pk2h(fa[3].z, fa[3].w);
            *(uint4*)(&As[nxt][arow * 40 + seg * 8]) = d0;
            *(uint4*)(&As[nxt][(arow + 128) * 40 + seg * 8]) = d1;
            uint4 q = dq_quad(wt, mk_ss(sv));
            *(uint4*)(&Bs[nxt][bn * 40 + kq * 8]) = q;
        }
        __syncthreads();
    }

    {
        const int cur = (H_ / 32 - 1) & 1;
        f16x8 bg0 = *(const f16x8*)(&Bs[cur][(nw * 32 + c16) * 40 + quad * 8]);
        f16x8 bg1 = *(const f16x8*)(&Bs[cur][(nw * 32 + 16 + c16) * 40 + quad * 8]);
        f16x8 bu0 = *(const f16x8*)(&Bs[cur][(64 + nw * 32 + c16) * 40 + quad * 8]);
        f16x8 bu1 = *(const f16x8*)(&Bs[cur][(64 + nw * 32 + 16 + c16) * 40 + quad * 8]);
#pragma unroll
        for (int f = 0; f < 4; ++f) {
            f16x8 af = *(const f16x8*)(&As[cur][(mw * 64 + f * 16 + c16) * 40 + quad * 8]);
            accg[f][0] = __builtin_amdgcn_mfma_f32_16x16x32_f16(af, bg0, accg[f][0], 0, 0, 0);
            accg[f][1] = __builtin_amdgcn_mfma_f32_16x16x32_f16(af, bg1, accg[f][1], 0, 0, 0);
            accu[f][0] = __builtin_amdgcn_mfma_f32_16x16x32_f16(af, bu0, accu[f][0], 0, 0, 0);
            accu[f][1] = __builtin_amdgcn_mfma_f32_16x16x32_f16(af, bu1, accu[f][1], 0, 0, 0);
        }
    }

    ushort_t* ip = inter + (size_t)zloc * T_ * I_;
#pragma unroll
    for (int f = 0; f < 4; ++f)
#pragma unroll
        for (int b = 0; b < 2; ++b)
#pragma unroll
            for (int r = 0; r < 4; ++r) {
                int row = mBase + mw * 64 + f * 16 + quad * 4 + r;
                int col = nTile * 64 + nw * 32 + b * 16 + c16;
                float g = accg[f][b][r];
                float u = accu[f][b][r];
                float v = u * g / (1.f + __expf(-g));
                half_t hv = (half_t)v;
                ushort_t hu;
                __builtin_memcpy(&hu, &hv, 2);
                ip[(size_t)row * I_ + col] = hu;
            }
}

// ==================== GEMM2: inter(f16) @ dequant(Wd) -> fp32 ====================
// A-staging via async global_load_lds into a LINEAR [256][32] tile with
// both-sides XOR swizzle (rule #21): physical slot (r,s) holds global chunk
// s ^ ((r>>1)&3). Write side: linear dest, pre-swizzled SOURCE. Read side:
// chunk quad of row r is at slot quad ^ ((r>>1)&3). Spreads the af b128
// reads 2-per-16B-slot (free) instead of the round-10 linear layout's 8-way.
__global__ __launch_bounds__(512, 4) void gemm2_kernel(
    const ushort_t* __restrict__ inter,
    const int* __restrict__ dp,
    const float* __restrict__ dsc,
    const float* __restrict__ gscale_p,
    float* __restrict__ out,
    int e0) {
    __shared__ __align__(16) ushort_t As[2][256 * 32]; // linear 64B rows (gload_lds: no pad)
    __shared__ __align__(16) ushort_t Bs[2][128 * 40];

    const int tid = threadIdx.x;
    const int lane = tid & 63, wv = tid >> 6;
    const int quad = lane >> 4, c16 = lane & 15;
    const int mw = wv >> 1, nw = wv & 1;
    const int zloc = blockIdx.z, e = e0 + zloc;
    const int mBase = blockIdx.y * 256, nBase = blockIdx.x * 128;
    const float gsc = gscale_p[0];

    const int kq = (tid >> 4) & 3;
    const int bn = (tid & 15) | ((tid >> 6) << 4);
    const int col = nBase + bn;
    const int* bptr = dp + (size_t)e * (I_ / 2) * H_ + (size_t)(kq * 4) * H_ + col;
    const float* sptr = dsc + (size_t)e * (I_ / 16) * H_ + (size_t)(kq >> 1) * H_ + col;

    // async-A with pre-swizzled source: lane l covers row wv*16 + l/4; its
    // linear dest slot is l&3, so it must LOAD global chunk (l&3)^((l>>3)&3)
    // (note (l>>3)&3 == (row>>1)&3). Each 4-lane row group still covers the
    // full 64B row -> coalescing unchanged.
    const int schunk = (lane & 3) ^ ((lane >> 3) & 3);
    const ushort_t* srcA = inter + (size_t)(zloc * T_ + mBase + wv * 16 + (lane >> 2)) * I_ + schunk * 8;
    const size_t srcA2off = (size_t)128 * I_;
    const int ldsAw = wv * 16 * 32; // ushort index of wave's dest base (call 0)

    // read-side swizzle key: rows read are mw*64 + f*16 + c16 (+128), so
    // (row>>1)&3 == (c16>>1)&3 for every f and both halves.
    const int qx = quad ^ ((c16 >> 1) & 3);

    f32x4 acc[4][4];
    const f32x4 z4 = {0.f, 0.f, 0.f, 0.f};
#pragma unroll
    for (int f = 0; f < 4; ++f)
#pragma unroll
        for (int b = 0; b < 4; ++b) acc[f][b] = z4;

    int wt[4]; float sv;
    // ---- prologue: tile 0 ----
    cp16_async(srcA, &As[0][ldsAw]);
    cp16_async(srcA + srcA2off, &As[0][128 * 32 + ldsAw]);
#pragma unroll
    for (int i = 0; i < 4; ++i) wt[i] = bptr[(size_t)i * H_];
    sv = sptr[0] * gsc;
    {
        uint4 q = dq_quad(wt, mk_ss(sv));
        *(uint4*)(&Bs[0][bn * 40 + kq * 8]) = q;
    }
    __syncthreads(); // drains vmcnt (gload_lds) + lgkm (ds_write)

    for (int kt = 0; kt < I_ / 32 - 1; ++kt) {
        const int cur = kt & 1, nxt = cur ^ 1;
        // ---- issue async A-copy for tile kt+1 (overlaps MFMA below) ----
        cp16_async(srcA + (size_t)(kt + 1) * 32, &As[nxt][ldsAw]);
        cp16_async(srcA + srcA2off + (size_t)(kt + 1) * 32, &As[nxt][128 * 32 + ldsAw]);
        // ---- B reg-prefetch tile kt+1 ----
        const int* bp = bptr + (size_t)(kt + 1) * 16 * H_;
#pragma unroll
        for (int i = 0; i < 4; ++i) wt[i] = bp[(size_t)i * H_];
        sv = sptr[(size_t)(kt + 1) * 2 * H_] * gsc;

        // ---- consume current ----
        f16x8 bfr[4];
#pragma unroll
        for (int b = 0; b < 4; ++b)
            bfr[b] = *(const f16x8*)(&Bs[cur][(nw * 64 + b * 16 + c16) * 40 + quad * 8]);
#pragma unroll
        for (int f = 0; f < 4; ++f) {
            f16x8 af = *(const f16x8*)(&As[cur][(mw * 64 + f * 16 + c16) * 32 + qx * 8]);
#pragma unroll
            for (int b = 0; b < 4; ++b)
                acc[f][b] = __builtin_amdgcn_mfma_f32_16x16x32_f16(af, bfr[b], acc[f][b], 0, 0, 0);
        }

        // ---- stage next B ----
        uint4 q = dq_quad(wt, mk_ss(sv));
        *(uint4*)(&Bs[nxt][bn * 40 + kq * 8]) = q;
        __syncthreads();
    }

    // ---- last tile ----
    {
        const int cur = (I_ / 32 - 1) & 1;
        f16x8 bfr[4];
#pragma unroll
        for (int b = 0; b < 4; ++b)
            bfr[b] = *(const f16x8*)(&Bs[cur][(nw * 64 + b * 16 + c16) * 40 + quad * 8]);
#pragma unroll
        for (int f = 0; f < 4; ++f) {
            f16x8 af = *(const f16x8*)(&As[cur][(mw * 64 + f * 16 + c16) * 32 + qx * 8]);
#pragma unroll
            for (int b = 0; b < 4; ++b)
                acc[f][b] = __builtin_amdgcn_mfma_f32_16x16x32_f16(af, bfr[b], acc[f][b], 0, 0, 0);
        }
    }

#pragma unroll
    for (int f = 0; f < 4; ++f)
#pragma unroll
        for (int b = 0; b < 4; ++b)
#pragma unroll
            for (int r = 0; r < 4; ++r) {
                int row = mBase + mw * 64 + f * 16 + quad * 4 + r;
                int c = nBase + nw * 64 + b * 16 + c16;
                out[(size_t)(e * T_ + row) * H_ + c] = acc[f][b][r];
            }
}

extern "C" void kernel_launch(void* const* d_in, const int* in_sizes, int n_in,
                              void* d_out, int out_size, void* d_ws, size_t ws_size,
                              hipStream_t stream) {
    const float* x = (const float*)d_in[0];
    const int* gup = (const int*)d_in[1];
    const float* gus = (const float*)d_in[2];
    const float* gug = (const float*)d_in[3];
    const int* dp = (const int*)d_in[4];
    const float* dsc = (const float*)d_in[5];
    const float* dg = (const float*)d_in[6];
    float* out = (float*)d_out;
    ushort_t* inter = (ushort_t*)d_ws;

    const size_t per_e = (size_t)T_ * I_ * 2;
    int C = 8;
    if (ws_size < 8 * per_e) C = (ws_size >= 4 * per_e) ? 4 : (ws_size >= 2 * per_e) ? 2 : 1;

    for (int e0 = 0; e0 < E_; e0 += C) {
        gemm1_kernel<<<dim3(I_ / 64, T_ / 256, C), 512, 0, stream>>>(x, gup, gus, gug, inter, e0);
        gemm2_kernel<<<dim3(H_ / 128, T_ / 256, C), 512, 0, stream>>>(inter, dp, dsc, dg, out, e0);
    }
}